// Round 11
// baseline (1553.597 us; speedup 1.0000x reference)
//
#include <hip/hip_runtime.h>
#include <hip/hip_bf16.h>

#define CI 8

typedef float f32x4 __attribute__((ext_vector_type(4)));
typedef _Float16 f16x8 __attribute__((ext_vector_type(8)));

union FragU { uint4 q; f16x8 h; };

// Base anchors, order a = ratio_idx*3 + scale_idx (verified vs numpy round-half-even)
__constant__ float BA[9][4] = {
    {-84.f,  -40.f,   99.f,  55.f},
    {-176.f, -88.f,  191.f, 103.f},
    {-360.f, -184.f, 375.f, 199.f},
    {-56.f,  -56.f,   71.f,  71.f},
    {-120.f, -120.f, 135.f, 135.f},
    {-248.f, -248.f, 263.f, 263.f},
    {-36.f,  -80.f,   51.f,  95.f},
    {-80.f,  -168.f,  95.f, 183.f},
    {-168.f, -344.f, 183.f, 359.f}
};

// Exact 3-way f16 split: v == h + m/2048 + l/2048^2  (exact; l has <=3 significant bits)
__device__ __forceinline__ void split3(float v, unsigned short& hu, unsigned short& mu, unsigned short& lu) {
    _Float16 h = (_Float16)v;
    float r1 = v - (float)h;                       // exact
    _Float16 m = (_Float16)(r1 * 2048.f);
    float r2 = r1 - (float)m * (1.f/2048.f);       // exact (Sterbenz)
    _Float16 l = (_Float16)(r2 * 4194304.f);       // exact
    __builtin_memcpy(&hu, &h, 2);
    __builtin_memcpy(&mu, &m, 2);
    __builtin_memcpy(&lu, &l, 2);
}

// ===================== split pre-passes =====================
// XT (granule layout, u16): [chunk 16][n 8][hp 66][wp 66][64 u16] rows 128 B.
//   Row wp holds 8 granules of 8 f16; stored position p contains logical granule
//   g = p ^ (wp&7); g<4 -> hi of ci=g*8+e ; g>=4 -> mid of ci=(g-4)*8+e.
//   Fragments read as direct ds_read_b128 (NO perms).
// XLF (lo f16): [chunk 16][n 8][hp 66][wp 66][40 u16] rows 80 B (32 used) — R3-verified.
__global__ __launch_bounds__(256) void split_x_kernel(
    const float* __restrict__ x, unsigned short* __restrict__ XT, unsigned short* __restrict__ XLF)
{
    int bid = blockIdx.x;                  // chunk*528 + n*66 + hp
    int hp = bid % 66; int t2 = bid / 66;
    int n = t2 & 7; int chunk = t2 >> 3;
    __shared__ float sx[32][64];
    int tid = threadIdx.x;
    int hin = hp - 1;
    bool rowvalid = (hin >= 0 && hin < 64);
    if (rowvalid) {
        for (int i = tid; i < 2048; i += 256) {
            int ci = i >> 6, w = i & 63;
            sx[ci][w] = x[(((size_t)(n*512 + chunk*32 + ci)) << 12) + (hin << 6) + w];
        }
    }
    __syncthreads();
    unsigned short* dst = XT + ((size_t)chunk * (8*66*66) + (size_t)(n*66 + hp) * 66) * 64;
    for (int o = tid; o < 66*64; o += 256) {
        int wp = o >> 6; int idx = o & 63;
        int p = idx >> 3, e = idx & 7;
        int g = p ^ (wp & 7);
        int ci = (g & 3)*8 + e;
        float v = 0.f;
        int win = wp - 1;
        if (rowvalid && win >= 0 && win < 64) v = sx[ci][win];
        unsigned short hu, mu, lu;
        split3(v, hu, mu, lu);
        dst[o] = (g < 4) ? hu : mu;
    }
    unsigned short* dstL = XLF + ((size_t)chunk * (8*66*66) + (size_t)(n*66 + hp) * 66) * 40;
    for (int o = tid; o < 66*40; o += 256) {
        int wp = o / 40, j = o - wp*40;
        float v = 0.f;
        if (j < 32) {
            int win = wp - 1;
            if (rowvalid && win >= 0 && win < 64) v = sx[j][win];
        }
        unsigned short hu, mu, lu;
        split3(v, hu, mu, lu);
        dstL[o] = lu;
    }
}

// WT2 (granule layout, u16): [co_t 8][chunk 16][tap 9][co_l 64][64 u16] rows 128 B,
//   stored position p holds logical g = p ^ (co_l&7) (read side uses l15&7; 16|64 ≡ 0 mod 8).
__global__ __launch_bounds__(256) void split_w2_kernel(
    const float* __restrict__ W, unsigned short* __restrict__ WT2)
{
    int gid = blockIdx.x * 256 + threadIdx.x;
    if (gid >= 4718592) return;
    int idx = gid & 63; int t = gid >> 6;
    int co_l = t & 63; t >>= 6;
    int tap = t % 9; t /= 9;
    int chunk = t & 15; int co_t = t >> 4;
    int p = idx >> 3, e = idx & 7;
    int g = p ^ (co_l & 7);
    int ci = chunk*32 + (g & 3)*8 + e;
    float v = W[((size_t)(co_t*64 + co_l)*512 + ci)*9 + tap];
    unsigned short hu, mu, lu;
    split3(v, hu, mu, lu);
    WT2[gid] = (g < 4) ? hu : mu;
}

// WLF (lo f16): [co_t 8][chunk 16][tap 9][co_l 64][40 u16] rows 80 B (32 used).
__global__ __launch_bounds__(256) void split_wlof_kernel(
    const float* __restrict__ W, unsigned short* __restrict__ WLF)
{
    int gid = blockIdx.x * 256 + threadIdx.x;
    if (gid >= 2949120) return;
    int j = gid % 40; int t = gid / 40;
    int co_l = t & 63; t >>= 6;
    int tap = t % 9; t /= 9;
    int chunk = t & 15; int co_t = t >> 4;
    float v = 0.f;
    if (j < 32) v = W[((size_t)(co_t*64 + co_l)*512 + chunk*32 + j)*9 + tap];
    unsigned short hu, mu, lu;
    split3(v, hu, mu, lu);
    WLF[gid] = lu;
}

// ===================== conv3x3 via exact 3xf16-split MFMA =====================
__device__ __forceinline__ void gll16(const void* gsrc, void* ldst) {
    __builtin_amdgcn_global_load_lds(
        (const __attribute__((address_space(1))) unsigned*)gsrc,
        (__attribute__((address_space(3))) unsigned*)ldst, 16, 0, 0);
}

// R10 structure widened to 8 waves (512 thr) for 2 waves/SIMD overlap.
// Block tile 64co x 256sp (4 rows x 64 cols) — identical LDS layouts/addresses to R10.
// Wave (wg = wv>>2, wrow = wv&3): computes row h0+wrow, all co (i 0..3), sp-half wg
// (t = wg*2 + tt, tt 0..1) -> disjoint outputs, no cross-wave reduction. acc[4][2]x3.
// LDS 123,328 B, 1 block/CU, 8 waves = 2/SIMD: ds_read latency and MFMA issue overlap
// across the SIMD's two waves (was fully serialized at 1 wave/SIMD in R10).
__global__ __launch_bounds__(512, 2) void conv3x3_mfma(
    const unsigned short* __restrict__ XT, const unsigned short* __restrict__ WT2,
    const unsigned short* __restrict__ XLF, const unsigned short* __restrict__ WLF,
    const float* __restrict__ bias, float* __restrict__ base)
{
    __shared__ __align__(16) unsigned lds[30832];   // 123328 B
    char* xPb = (char*)lds;             // 50688
    char* xLb = (char*)lds + 50688;     // 31680
    char* wPb = (char*)lds + 82368;     // 24576
    char* wLb = (char*)lds + 106944;    // 16384

    int tid = threadIdx.x;
    int lane = tid & 63;
    int wv = tid >> 6;          // 0..7
    int wg = wv >> 2;           // sp-half
    int wrow = wv & 3;          // row within tile
    int l15 = lane & 15, lg = lane >> 4;

    int bid = blockIdx.x;
    int co_t = bid & 7;            // R3/R5-verified mapping (FETCH ~480MB)
    int spid = bid >> 3;           // 0..127
    int n = spid >> 4;
    int h0 = (spid & 15) * 4;

    const char* XTb  = (const char*)XT;
    const char* WTb  = (const char*)WT2;
    const char* XLFb = (const char*)XLF;
    const char* WLFb = (const char*)WLF;
    size_t xgbase  = (size_t)(n*66 + h0) * 8448;   // 66 wp * 128 B
    size_t xlbase  = (size_t)(n*66 + h0) * 5280;   // 66 wp * 80 B

    f32x4 acc1[4][2], acc2[4][2], acc3[4][2];
    for (int i = 0; i < 4; ++i)
        for (int t = 0; t < 2; ++t) {
            acc1[i][t] = (f32x4){0.f,0.f,0.f,0.f};
            acc2[i][t] = (f32x4){0.f,0.f,0.f,0.f};
            acc3[i][t] = (f32x4){0.f,0.f,0.f,0.f};
        }

    for (int chunk = 0; chunk < 16; ++chunk) {
        __syncthreads();                          // prev chunk compute done, all LDS free
        const char* xsrc  = XTb  + (size_t)chunk * 4460544 + xgbase;
        const char* xlsrc = XLFb + (size_t)chunk * 2787840 + xlbase;
        const char* wsrc  = WTb  + (size_t)(co_t*16 + chunk) * 73728;
        const char* wlsrc = WLFb + (size_t)(co_t*16 + chunk) * 46080;
        // X hi|mid: 50 x 1024B (last overlaps)
        for (int s = 0; s < 7; ++s) {
            int L = wv + s*8;
            if (L < 50) { int db = (L < 49) ? L*1024 : 49664; gll16(xsrc + db + lane*16, xPb + db); }
        }
        // X lo f16: 31 loads (last overlaps)
        for (int s = 0; s < 4; ++s) {
            int L = wv + s*8;
            if (L < 31) { int db = (L < 30) ? L*1024 : 30656; gll16(xlsrc + db + lane*16, xLb + db); }
        }
        // W kh=0: hi|mid 24 loads + lo 16 loads
        for (int s = 0; s < 3; ++s) {
            int L = wv + s*8;
            gll16(wsrc + L*1024 + lane*16, wPb + L*1024);
        }
        for (int s = 0; s < 2; ++s) {
            int L = wv + s*8;
            gll16(wlsrc + L*1024 + lane*16, wLb + L*1024);
        }
        __syncthreads();                          // chunk X + W[kh0] staged

#pragma unroll
        for (int kh = 0; kh < 3; ++kh) {
            if (kh) {
                __syncthreads();                  // prev kh compute done (wP/wL free)
                for (int s = 0; s < 3; ++s) {
                    int L = wv + s*8;
                    gll16(wsrc + kh*24576 + L*1024 + lane*16, wPb + L*1024);
                }
                for (int s = 0; s < 2; ++s) {
                    int L = wv + s*8;
                    gll16(wlsrc + kh*15360 + L*1024 + lane*16, wLb + L*1024);
                }
                __syncthreads();                  // staged
            }
            int rbase = (wrow + kh) * 66;
#pragma unroll
            for (int kw = 0; kw < 3; ++kw) {
                FragU a1[4], a2[4], a3[4];
#pragma unroll
                for (int i = 0; i < 4; ++i) {
                    int rW = kw*64 + i*16 + l15;
                    const char* pa = wPb + rW*128;
                    int o1 = (lg ^ (l15 & 7)) << 4;
                    a1[i].q = *(const uint4*)(pa + o1);
                    a2[i].q = *(const uint4*)(pa + (o1 ^ 64));
                    a3[i].q = *(const uint4*)(wLb + rW*80 + lg*16);
                }
#pragma unroll
                for (int tt = 0; tt < 2; ++tt) {
                    int wp = (wg*2 + tt)*16 + l15 + kw;
                    int rowB = rbase + wp;
                    const char* pb = xPb + rowB*128;
                    int o2 = (lg ^ (wp & 7)) << 4;
                    FragU b1, b2, b3;
                    b1.q = *(const uint4*)(pb + o2);
                    b2.q = *(const uint4*)(pb + (o2 ^ 64));
                    b3.q = *(const uint4*)(xLb + rowB*80 + lg*16);
#pragma unroll
                    for (int i = 0; i < 4; ++i) {
                        acc1[i][tt] = __builtin_amdgcn_mfma_f32_16x16x32_f16(a1[i].h, b1.h, acc1[i][tt], 0, 0, 0);
                        acc2[i][tt] = __builtin_amdgcn_mfma_f32_16x16x32_f16(a1[i].h, b2.h, acc2[i][tt], 0, 0, 0);
                        acc2[i][tt] = __builtin_amdgcn_mfma_f32_16x16x32_f16(a2[i].h, b1.h, acc2[i][tt], 0, 0, 0);
                        acc3[i][tt] = __builtin_amdgcn_mfma_f32_16x16x32_f16(a1[i].h, b3.h, acc3[i][tt], 0, 0, 0);
                        acc3[i][tt] = __builtin_amdgcn_mfma_f32_16x16x32_f16(a3[i].h, b1.h, acc3[i][tt], 0, 0, 0);
                        acc3[i][tt] = __builtin_amdgcn_mfma_f32_16x16x32_f16(a2[i].h, b2.h, acc3[i][tt], 0, 0, 0);
                    }
                }
            }
        }
    }

    // epilogue: co = co_t*64 + i*16 + lg*4 + r ; h = h0+wrow ; wcol = (wg*2+tt)*16 + l15
    int hrow = h0 + wrow;
#pragma unroll
    for (int i = 0; i < 4; ++i) {
#pragma unroll
        for (int tt = 0; tt < 2; ++tt) {
            f32x4 v = acc1[i][tt] + acc2[i][tt] * (1.0f/2048.0f) + acc3[i][tt] * (1.0f/4194304.0f);
#pragma unroll
            for (int r = 0; r < 4; ++r) {
                int co = co_t*64 + i*16 + lg*4 + r;
                float o = v[r] + bias[co];
                o = o > 0.f ? o : 0.f;
                base[(((size_t)(n*512 + co)) << 12) + (hrow << 6) + (wg*2 + tt)*16 + l15] = o;
            }
        }
    }
}

// ===================== fallback fp32 conv (used if ws too small) =====================
__global__ __launch_bounds__(256) void conv3x3_relu(
    const float* __restrict__ x, const float* __restrict__ W,
    const float* __restrict__ bias, float* __restrict__ base)
{
    int bid  = blockIdx.x;
    int co_t = bid >> 8;
    int rem  = bid & 255;
    int n    = rem >> 5;
    int row_t= rem & 31;
    int row0 = row_t * 2;

    __shared__ float sIn[CI][4][66];
    __shared__ float sW[CI][9][64];

    int tid = threadIdx.x;
    int cg  = tid >> 4;
    int sg  = tid & 15;
    int out_r = sg >> 3;
    int wb  = (sg & 7) * 8;

    float acc[4][8];
#pragma unroll
    for (int a = 0; a < 4; ++a)
#pragma unroll
        for (int q = 0; q < 8; ++q) acc[a][q] = 0.f;

    const float* xn = x + (size_t)n * 512 * 4096;

    for (int c = 0; c < 64; ++c) {
        for (int idx = tid; idx < CI * 4 * 66; idx += 256) {
            int ci = idx / 264; int r2 = idx % 264;
            int ir = r2 / 66;   int col = r2 % 66;
            int h = row0 - 1 + ir; int w = col - 1;
            float v = 0.f;
            if ((unsigned)h < 64u && (unsigned)w < 64u)
                v = xn[(((size_t)(c * CI + ci)) << 12) + (h << 6) + w];
            sIn[ci][ir][col] = v;
        }
        {
            int co = tid >> 2; int part = tid & 3;
            const float* wp = W + ((size_t)(co_t * 64 + co) * 512 + c * CI) * 9;
#pragma unroll
            for (int q = 0; q < 18; ++q) {
                int j = part * 18 + q;
                int ci = j / 9; int k = j % 9;
                sW[ci][k][co] = wp[j];
            }
        }
        __syncthreads();

#pragma unroll
        for (int ci = 0; ci < CI; ++ci) {
            float in10[3][10];
#pragma unroll
            for (int kh = 0; kh < 3; ++kh)
#pragma unroll
                for (int q = 0; q < 10; ++q)
                    in10[kh][q] = sIn[ci][out_r + kh][wb + q];
#pragma unroll
            for (int kh = 0; kh < 3; ++kh) {
#pragma unroll
                for (int kw = 0; kw < 3; ++kw) {
                    float4 wv = *(const float4*)&sW[ci][kh * 3 + kw][cg * 4];
#pragma unroll
                    for (int wo = 0; wo < 8; ++wo) {
                        float iv = in10[kh][wo + kw];
                        acc[0][wo] += iv * wv.x;
                        acc[1][wo] += iv * wv.y;
                        acc[2][wo] += iv * wv.z;
                        acc[3][wo] += iv * wv.w;
                    }
                }
            }
        }
        __syncthreads();
    }

    int h = row0 + out_r;
#pragma unroll
    for (int a = 0; a < 4; ++a) {
        int co = co_t * 64 + cg * 4 + a;
        float b = bias[co];
        float* dst = base + (((size_t)(n * 512 + co)) << 12) + (h << 6) + wb;
#pragma unroll
        for (int wo = 0; wo < 8; ++wo) {
            float v = acc[a][wo] + b;
            dst[wo] = v > 0.f ? v : 0.f;
        }
    }
}

// ===================== 1x1 heads (256 thr: 128 pos x 2 output-halves) =====================
__global__ __launch_bounds__(256) void heads_1x1(
    const float* __restrict__ base,
    const float* __restrict__ Wc, const float* __restrict__ bc,
    const float* __restrict__ Wr, const float* __restrict__ br,
    float* __restrict__ out_score, float* __restrict__ out_reg,
    float* __restrict__ fg)
{
    __shared__ float sW[128][56];
    int tid = threadIdx.x;
    int half = tid >> 7;           // 0: outputs 0..27, 1: outputs 28..55
    int pt = tid & 127;
    int pos = blockIdx.x * 128 + pt;
    int n = pos >> 12; int hw = pos & 4095;

    float acc[28];
#pragma unroll
    for (int o = 0; o < 28; ++o) acc[o] = 0.f;

    for (int c0 = 0; c0 < 512; c0 += 128) {
        for (int idx = tid; idx < 128 * 56; idx += 256) {
            int cc = idx & 127; int o = idx >> 7;
            float wv = 0.f;
            if (o < 18)       wv = Wc[o * 512 + c0 + cc];
            else if (o < 54)  wv = Wr[(o - 18) * 512 + c0 + cc];
            sW[cc][o] = wv;
        }
        __syncthreads();
        for (int cc = 0; cc < 128; ++cc) {
            float bval = base[(((size_t)(n * 512 + c0 + cc)) << 12) + hw];
#pragma unroll
            for (int og = 0; og < 7; ++og) {
                float4 w4 = *(const float4*)&sW[cc][half*28 + og * 4];
                acc[og * 4 + 0] += bval * w4.x;
                acc[og * 4 + 1] += bval * w4.y;
                acc[og * 4 + 2] += bval * w4.z;
                acc[og * 4 + 3] += bval * w4.w;
            }
        }
        __syncthreads();
    }
#pragma unroll
    for (int o = 0; o < 28; ++o) {
        int go = half*28 + o;
        if (go < 18) acc[o] += bc[go];
        else if (go < 54) acc[o] += br[go - 18];
    }

    float* outs = out_score + (size_t)n * 73728 + (size_t)hw * 18;
    float* outr = out_reg + (size_t)n * 147456 + (size_t)hw * 36;
    if (half == 0) {
#pragma unroll
        for (int o = 0; o < 18; ++o) outs[o] = acc[o];
#pragma unroll
        for (int o = 18; o < 28; ++o) outr[o - 18] = acc[o];
#pragma unroll
        for (int a = 0; a < 9; ++a) {
            float s0 = acc[a * 2], s1 = acc[a * 2 + 1];
            float m = fmaxf(s0, s1);
            float e0 = expf(s0 - m), e1 = expf(s1 - m);
            fg[(size_t)n * 36864 + (size_t)hw * 9 + a] = e1 / (e0 + e1);
        }
    } else {
#pragma unroll
        for (int o = 0; o < 26; ++o) outr[10 + o] = acc[o];   // go 28..53 -> reg 10..35
    }
}

// ===================== decode + clip + valid + sort key =====================
__global__ __launch_bounds__(256) void decode_kernel(
    const float* __restrict__ out_reg, const float* __restrict__ fg,
    const int* __restrict__ ih_p, const int* __restrict__ iw_p,
    float4* __restrict__ boxes, unsigned long long* __restrict__ keys)
{
    int gid = blockIdx.x * 256 + threadIdx.x;
    if (gid >= 8 * 36864) return;
    int n = gid / 36864; int i = gid - n * 36864;
    int a = i % 9; int hw = i / 9; int h = hw >> 6; int w = hw & 63;
    float shx = w * 16.f, shy = h * 16.f;
    float x1 = BA[a][0] + shx, y1 = BA[a][1] + shy;
    float x2 = BA[a][2] + shx, y2 = BA[a][3] + shy;
    float wa = x2 - x1 + 1.f, ha = y2 - y1 + 1.f;
    float cxa = x1 + 0.5f * wa, cya = y1 + 0.5f * ha;
    float4 d = *(const float4*)(out_reg + (size_t)n * 147456 + (size_t)i * 4);
    float dw = fminf(fmaxf(d.z, -4.f), 4.f);
    float dh = fminf(fmaxf(d.w, -4.f), 4.f);
    float cx = d.x * wa + cxa, cy = d.y * ha + cya;
    float bw = wa * expf(dw), bh = ha * expf(dh);
    float fw = (float)(*iw_p) - 1.f, fh = (float)(*ih_p) - 1.f;
    float bx1 = fminf(fmaxf(cx - 0.5f * bw, 0.f), fw);
    float by1 = fminf(fmaxf(cy - 0.5f * bh, 0.f), fh);
    float bx2 = fminf(fmaxf(cx + 0.5f * bw, 0.f), fw);
    float by2 = fminf(fmaxf(cy + 0.5f * bh, 0.f), fh);
    boxes[gid] = make_float4(bx1, by1, bx2, by2);
    float ws_ = bx2 - bx1 + 1.f, hs_ = by2 - by1 + 1.f;
    bool valid = (ws_ >= 16.f) && (hs_ >= 16.f);
    float s = valid ? fg[gid] : -1e9f;
    unsigned int u = __float_as_uint(s);
    unsigned int ks = (u & 0x80000000u) ? ~u : (u | 0x80000000u);
    keys[gid] = ((unsigned long long)ks << 32) | (unsigned long long)(0xFFFFFFFFu - (unsigned)i);
}

// ===================== exact top-1000 via radix-select + bitonic sort =====================
__global__ __launch_bounds__(1024) void topk_kernel(
    const unsigned long long* __restrict__ keys,
    const float4* __restrict__ boxes,
    float4* __restrict__ top_boxes,
    unsigned long long* __restrict__ validmask)
{
    int b = blockIdx.x; int tid = threadIdx.x;
    const unsigned long long* kb = keys + (size_t)b * 36864;
    __shared__ unsigned int hist[256];
    __shared__ unsigned long long s_prefix;
    __shared__ int s_rank;
    __shared__ int s_cnt;
    __shared__ unsigned long long top[1024];
    if (tid == 0) { s_prefix = 0ull; s_rank = 1000; s_cnt = 0; }
    __syncthreads();

    for (int pass = 0; pass < 8; ++pass) {
        int shift = 56 - 8 * pass;
        if (tid < 256) hist[tid] = 0u;
        __syncthreads();
        unsigned long long pref = s_prefix;
        unsigned long long maskHigh = (pass == 0) ? 0ull : ((~0ull) << (shift + 8));
        for (int i = tid; i < 36864; i += 1024) {
            unsigned long long k = kb[i];
            if ((k & maskHigh) == (pref & maskHigh))
                atomicAdd(&hist[(unsigned)(k >> shift) & 255u], 1u);
        }
        __syncthreads();
        if (tid == 0) {
            int r = s_rank; int cum = 0; int B = 0;
            for (int v = 255; v >= 0; --v) {
                int c = (int)hist[v];
                if (cum + c >= r) { B = v; s_rank = r - cum; break; }
                cum += c;
            }
            s_prefix = s_prefix | ((unsigned long long)B << shift);
        }
        __syncthreads();
    }
    unsigned long long T = s_prefix;

    top[tid] = 0ull;
    __syncthreads();
    for (int i = tid; i < 36864; i += 1024) {
        unsigned long long k = kb[i];
        if (k >= T) { int p = atomicAdd(&s_cnt, 1); top[p] = k; }
    }
    __syncthreads();

    for (int k = 2; k <= 1024; k <<= 1) {
        for (int j = k >> 1; j > 0; j >>= 1) {
            int p = tid ^ j;
            unsigned long long xv = top[tid], yv = top[p];
            bool lower = tid < p;
            bool descBlock = ((tid & k) == 0);
            unsigned long long mn = xv < yv ? xv : yv;
            unsigned long long mx = xv < yv ? yv : xv;
            unsigned long long keep = descBlock ? (lower ? mx : mn) : (lower ? mn : mx);
            __syncthreads();
            top[tid] = keep;
            __syncthreads();
        }
    }

    bool validf = false;
    if (tid < 1000) {
        unsigned long long k = top[tid];
        unsigned int inv = (unsigned)(k & 0xFFFFFFFFull);
        unsigned int idx = 0xFFFFFFFFu - inv;
        unsigned int ks = (unsigned)(k >> 32);
        unsigned int u = (ks & 0x80000000u) ? (ks ^ 0x80000000u) : ~ks;
        float s = __uint_as_float(u);
        validf = (s > -5e8f);
        top_boxes[(size_t)b * 1000 + tid] = boxes[(size_t)b * 36864 + idx];
    }
    unsigned long long bal = __ballot(validf);
    if ((tid & 63) == 0) {
        int wvi = tid >> 6;
        if (wvi < 16) validmask[b * 16 + wvi] = bal;
    }
}

// ===================== NMS =====================
__global__ __launch_bounds__(256) void nms_sup(
    const float4* __restrict__ top_boxes, unsigned long long* __restrict__ sup)
{
    int b = blockIdx.y;
    __shared__ float4 sb[1000];
    int tid = threadIdx.x;
    for (int i = tid; i < 1000; i += 256) sb[i] = top_boxes[(size_t)b * 1000 + i];
    __syncthreads();
    int i = blockIdx.x * 16 + (tid >> 4);
    int wword = tid & 15;
    if (i >= 1000) return;
    float4 bi = sb[i];
    float areai = (bi.z - bi.x + 1.f) * (bi.w - bi.y + 1.f);
    unsigned long long m = 0ull;
    int j0 = wword * 64;
#pragma unroll 4
    for (int jj = 0; jj < 64; ++jj) {
        int j = j0 + jj;
        if (j > i && j < 1000) {
            float4 bj = sb[j];
            float ix1 = fmaxf(bi.x, bj.x), iy1 = fmaxf(bi.y, bj.y);
            float ix2 = fminf(bi.z, bj.z), iy2 = fminf(bi.w, bj.w);
            float iw = fmaxf(ix2 - ix1 + 1.f, 0.f), ih2 = fmaxf(iy2 - iy1 + 1.f, 0.f);
            float inter = iw * ih2;
            float areaj = (bj.z - bj.x + 1.f) * (bj.w - bj.y + 1.f);
            float iou = inter / (areai + areaj - inter);
            if (iou > 0.7f) m |= (1ull << jj);
        }
    }
    sup[((size_t)b * 1000 + i) * 16 + wword] = m;
}

// sequential NMS scan with register-group prefetch (64 rows/group, double-buffered)
__global__ __launch_bounds__(64) void nms_scan(
    const unsigned long long* __restrict__ sup,
    const unsigned long long* __restrict__ validmask,
    const float4* __restrict__ top_boxes,
    float* __restrict__ rois, float* __restrict__ counts)
{
    int b = blockIdx.x; int lane = threadIdx.x;
    const unsigned long long* supb = sup + (size_t)b * 16000;
    int sub = lane >> 4;
    int word = lane & 15;

    unsigned long long bufA[16], bufB[16];
    unsigned long long remv = 0ull, keepw = 0ull;

#define PRELOAD(dst, g1)                                                   \
    _Pragma("unroll")                                                      \
    for (int k = 0; k < 16; ++k) {                                         \
        int r = (g1)*64 + k*4 + sub;                                       \
        if (r > 999) r = 999;                                              \
        dst[k] = supb[(size_t)r*16 + word];                                \
    }

#define PROCESS(buf, g)                                                    \
    _Pragma("unroll")                                                      \
    for (int ii = 0; ii < 64; ++ii) {                                      \
        int i = (g)*64 + ii;                                               \
        if (i < 1000) {                                                    \
            unsigned long long rw = __shfl(remv, (g), 64);                 \
            bool kept = !((rw >> ii) & 1ull);                              \
            unsigned long long rowv = __shfl(buf[ii>>2], ((ii&3)<<4) | word, 64); \
            if (kept) {                                                    \
                remv |= rowv;                                              \
                if (lane == (g)) keepw |= (1ull << ii);                    \
            }                                                              \
        }                                                                  \
    }

    PRELOAD(bufA, 0)
    for (int gp = 0; gp < 8; ++gp) {
        PRELOAD(bufB, gp*2 + 1)
        PROCESS(bufA, gp*2)
        if (gp < 7) { PRELOAD(bufA, gp*2 + 2) }
        PROCESS(bufB, gp*2 + 1)
    }
#undef PRELOAD
#undef PROCESS

    if (lane < 16) keepw &= validmask[b * 16 + lane];
    int cnt = (lane < 16) ? __popcll(keepw) : 0;
    int inc = cnt;
    for (int off = 1; off < 16; off <<= 1) {
        int t = __shfl_up(inc, off, 64);
        if (lane >= off) inc += t;
    }
    int total = __shfl(inc, 15, 64);
    int pre = inc - cnt;
    int count = total < 300 ? total : 300;

    float4* ro = (float4*)(rois + (size_t)b * 1200);
    for (int s = count + lane; s < 300; s += 64)
        ro[s] = make_float4(0.f, 0.f, 0.f, 0.f);
    for (int i = lane; i < 1000; i += 64) {
        int w = i >> 6, bit = i & 63;
        unsigned long long kw = __shfl(keepw, w, 64);
        int prew = __shfl(pre, w, 64);
        if ((kw >> bit) & 1ull) {
            int rank = prew + __popcll(kw & ((1ull << bit) - 1ull));
            if (rank < 300)
                ro[rank] = top_boxes[(size_t)b * 1000 + i];
        }
    }
    if (lane == 0) counts[b] = (float)count;
}

// ===================== launch =====================
extern "C" void kernel_launch(void* const* d_in, const int* in_sizes, int n_in,
                              void* d_out, int out_size, void* d_ws, size_t ws_size,
                              hipStream_t stream) {
    const float* x  = (const float*)d_in[0];
    const float* Wb = (const float*)d_in[1];
    const float* bb = (const float*)d_in[2];
    const float* Wc = (const float*)d_in[3];
    const float* bc = (const float*)d_in[4];
    const float* Wr = (const float*)d_in[5];
    const float* br = (const float*)d_in[6];
    const int* ih   = (const int*)d_in[7];
    const int* iw   = (const int*)d_in[8];

    float* out       = (float*)d_out;
    float* out_score = out;
    float* out_reg   = out + 589824;
    float* rois      = out + 589824 + 1179648;
    float* counts    = rois + 9600;

    char* ws = (char*)d_ws;
    float* fg                      = (float*)(ws);                        // 1,179,648
    float4* boxes                  = (float4*)(ws + 1179648);             // 4,718,592
    unsigned long long* keys       = (unsigned long long*)(ws + 5898240); // 2,359,296
    float4* top_boxes              = (float4*)(ws + 8257536);             // 128,000
    unsigned long long* sup        = (unsigned long long*)(ws + 8385536); // 1,024,000
    unsigned long long* validmask  = (unsigned long long*)(ws + 9409536); // 1,024
    float* base                    = (float*)(ws + 9410560);              // 67,108,864
    unsigned short* XT             = (unsigned short*)(ws + 76519424);    // 71,368,704
    unsigned short* WT2            = (unsigned short*)(ws + 147888128);   //  9,437,184
    unsigned short* XLF            = (unsigned short*)(ws + 157325312);   // 44,605,440
    unsigned short* WLF            = (unsigned short*)(ws + 201930752);   //  5,898,240 (+4096 pad)
    const size_t NEED_MFMA = 207837184;

    if (ws_size >= NEED_MFMA) {
        split_x_kernel<<<16*8*66, 256, 0, stream>>>(x, XT, XLF);
        split_w2_kernel<<<(4718592 + 255)/256, 256, 0, stream>>>(Wb, WT2);
        split_wlof_kernel<<<(2949120 + 255)/256, 256, 0, stream>>>(Wb, WLF);
        conv3x3_mfma<<<1024, 512, 0, stream>>>(XT, WT2, XLF, WLF, bb, base);
    } else {
        conv3x3_relu<<<2048, 256, 0, stream>>>(x, Wb, bb, base);
    }
    heads_1x1<<<256, 256, 0, stream>>>(base, Wc, bc, Wr, br, out_score, out_reg, fg);
    decode_kernel<<<1152, 256, 0, stream>>>(out_reg, fg, ih, iw, boxes, keys);
    topk_kernel<<<8, 1024, 0, stream>>>(keys, boxes, top_boxes, validmask);
    nms_sup<<<dim3(63, 8), 256, 0, stream>>>(top_boxes, sup);
    nms_scan<<<8, 64, 0, stream>>>(sup, validmask, top_boxes, rois, counts);
}

// Round 12
// 1218.325 us; speedup vs baseline: 1.2752x; 1.2752x over previous
//
#include <hip/hip_runtime.h>
#include <hip/hip_bf16.h>

#define CI 8

typedef float f32x4 __attribute__((ext_vector_type(4)));
typedef _Float16 f16x8 __attribute__((ext_vector_type(8)));

union FragU { uint4 q; f16x8 h; };

// Base anchors, order a = ratio_idx*3 + scale_idx (verified vs numpy round-half-even)
__constant__ float BA[9][4] = {
    {-84.f,  -40.f,   99.f,  55.f},
    {-176.f, -88.f,  191.f, 103.f},
    {-360.f, -184.f, 375.f, 199.f},
    {-56.f,  -56.f,   71.f,  71.f},
    {-120.f, -120.f, 135.f, 135.f},
    {-248.f, -248.f, 263.f, 263.f},
    {-36.f,  -80.f,   51.f,  95.f},
    {-80.f,  -168.f,  95.f, 183.f},
    {-168.f, -344.f, 183.f, 359.f}
};

// Exact 3-way f16 split: v == h + m/2048 + l/2048^2  (l has <=3 significant bits ->
// exactly representable as e5m2 = top byte of its f16 bits; R6/R7-verified)
__device__ __forceinline__ void split3(float v, unsigned short& hu, unsigned short& mu, unsigned short& lu) {
    _Float16 h = (_Float16)v;
    float r1 = v - (float)h;                       // exact
    _Float16 m = (_Float16)(r1 * 2048.f);
    float r2 = r1 - (float)m * (1.f/2048.f);       // exact (Sterbenz)
    _Float16 l = (_Float16)(r2 * 4194304.f);       // exact
    __builtin_memcpy(&hu, &h, 2);
    __builtin_memcpy(&mu, &m, 2);
    __builtin_memcpy(&lu, &l, 2);
}

// ===================== split pre-passes =====================
// XT (granule layout, u16): [chunk 16][n 8][hp 66][wp 66][64 u16] rows 128 B.
//   Stored position p holds logical granule g = p ^ (wp&7); g<4 -> hi of ci=g*8+e,
//   g>=4 -> mid. Fragments read as direct ds_read_b128 (no perms). R10-verified.
// XL8 (lo e5m2 byte): [chunk 16][n 8][hp 66][wp 66][40 B] rows 40 B (32 used). R7-verified.
__global__ __launch_bounds__(256) void split_x_kernel(
    const float* __restrict__ x, unsigned short* __restrict__ XT, unsigned char* __restrict__ XL8)
{
    int bid = blockIdx.x;                  // chunk*528 + n*66 + hp
    int hp = bid % 66; int t2 = bid / 66;
    int n = t2 & 7; int chunk = t2 >> 3;
    __shared__ float sx[32][64];
    int tid = threadIdx.x;
    int hin = hp - 1;
    bool rowvalid = (hin >= 0 && hin < 64);
    if (rowvalid) {
        for (int i = tid; i < 2048; i += 256) {
            int ci = i >> 6, w = i & 63;
            sx[ci][w] = x[(((size_t)(n*512 + chunk*32 + ci)) << 12) + (hin << 6) + w];
        }
    }
    __syncthreads();
    unsigned short* dst = XT + ((size_t)chunk * (8*66*66) + (size_t)(n*66 + hp) * 66) * 64;
    for (int o = tid; o < 66*64; o += 256) {
        int wp = o >> 6; int idx = o & 63;
        int p = idx >> 3, e = idx & 7;
        int g = p ^ (wp & 7);
        int ci = (g & 3)*8 + e;
        float v = 0.f;
        int win = wp - 1;
        if (rowvalid && win >= 0 && win < 64) v = sx[ci][win];
        unsigned short hu, mu, lu;
        split3(v, hu, mu, lu);
        dst[o] = (g < 4) ? hu : mu;
    }
    unsigned char* dstL = XL8 + ((size_t)chunk * (8*66*66) + (size_t)(n*66 + hp) * 66) * 40;
    for (int o = tid; o < 66*40; o += 256) {
        int wp = o / 40, j = o - wp*40;
        float v = 0.f;
        if (j < 32) {
            int win = wp - 1;
            if (rowvalid && win >= 0 && win < 64) v = sx[j][win];
        }
        unsigned short hu, mu, lu;
        split3(v, hu, mu, lu);
        dstL[o] = (unsigned char)(((unsigned)lu + 0x80u) >> 8);
    }
}

// Merged W split: WT2 granule u16 [co_t 8][chunk 16][tap 9][co_l 64][64 u16] (p holds
// g = p ^ (co_l&7); R10-verified) + WL8 e5m2 [co_t 8][chunk 16][tap 9][co_l 64][40 B]
// (R7-verified).
__global__ __launch_bounds__(256) void split_w_kernel(
    const float* __restrict__ W, unsigned short* __restrict__ WT2, unsigned char* __restrict__ WL8)
{
    int gid = blockIdx.x * 256 + threadIdx.x;
    if (gid < 4718592) {
        int idx = gid & 63; int t = gid >> 6;
        int co_l = t & 63; t >>= 6;
        int tap = t % 9; t /= 9;
        int chunk = t & 15; int co_t = t >> 4;
        int p = idx >> 3, e = idx & 7;
        int g = p ^ (co_l & 7);
        int ci = chunk*32 + (g & 3)*8 + e;
        float v = W[((size_t)(co_t*64 + co_l)*512 + ci)*9 + tap];
        unsigned short hu, mu, lu;
        split3(v, hu, mu, lu);
        WT2[gid] = (g < 4) ? hu : mu;
    } else if (gid < 4718592 + 2949120) {
        int g2 = gid - 4718592;
        int j = g2 % 40; int t = g2 / 40;
        int co_l = t & 63; t >>= 6;
        int tap = t % 9; t /= 9;
        int chunk = t & 15; int co_t = t >> 4;
        float v = 0.f;
        if (j < 32) v = W[((size_t)(co_t*64 + co_l)*512 + chunk*32 + j)*9 + tap];
        unsigned short hu, mu, lu;
        split3(v, hu, mu, lu);
        WL8[g2] = (unsigned char)(((unsigned)lu + 0x80u) >> 8);
    }
}

// ===================== conv3x3 via exact 3xf16-split MFMA =====================
__device__ __forceinline__ void gll16(const void* gsrc, void* ldst) {
    __builtin_amdgcn_global_load_lds(
        (const __attribute__((address_space(1))) unsigned*)gsrc,
        (__attribute__((address_space(3))) unsigned*)ldst, 16, 0, 0);
}

// e5m2 bytes -> f16: f16 bits = byte<<8 (exact). One v_perm per 2 elems. R6/R7-verified.
__device__ __forceinline__ void expand8(uint2 v, FragU& f) {
    f.q.x = __builtin_amdgcn_perm(0u, v.x, 0x01040004u);  // [0,b0,0,b1]
    f.q.y = __builtin_amdgcn_perm(0u, v.x, 0x03040204u);  // [0,b2,0,b3]
    f.q.z = __builtin_amdgcn_perm(0u, v.y, 0x01040004u);
    f.q.w = __builtin_amdgcn_perm(0u, v.y, 0x03040204u);
}

// R10 structure (875us verified) with e5m2 lo: 256 thr (4 waves), 1 block/CU.
// Tile 64co x 256sp (4 rows x 64 cols), wave wv -> row h0+wv, acc[4][4]x{1,2,3}.
// LDS 98,784 B: xP 50688 (granule hi|mid) | xL8 15840 (40B rows, e5m2) | wP 24576
// (per-kh granule) | wL8 7680 (per-kh, 40B rows e5m2). All operands LDS-staged.
// LDS/tap: 16 b128 + 8 b64 (was 24 b128, -17%); staging -26% bytes; b3/a3 frags
// uint2 frees ~24 VGPR for compiler cross-tap pipelining.
__global__ __launch_bounds__(256, 1) void conv3x3_mfma(
    const unsigned short* __restrict__ XT, const unsigned short* __restrict__ WT2,
    const unsigned char* __restrict__ XL8, const unsigned char* __restrict__ WL8,
    const float* __restrict__ bias, float* __restrict__ base)
{
    __shared__ __align__(16) unsigned lds[24696];   // 98784 B
    char* xPb = (char*)lds;             // 50688
    char* xLb = (char*)lds + 50688;     // 15840
    char* wPb = (char*)lds + 66528;     // 24576
    char* wLb = (char*)lds + 91104;     //  7680

    int tid = threadIdx.x;
    int lane = tid & 63;
    int wv = tid >> 6;
    int l15 = lane & 15, lg = lane >> 4;

    int bid = blockIdx.x;
    int co_t = bid & 7;            // R3/R5/R10-verified mapping (FETCH ~480MB)
    int spid = bid >> 3;           // 0..127
    int n = spid >> 4;
    int h0 = (spid & 15) * 4;

    const char* XTb  = (const char*)XT;
    const char* WTb  = (const char*)WT2;
    const char* XL8b = (const char*)XL8;
    const char* WL8b = (const char*)WL8;
    size_t xgbase  = (size_t)(n*66 + h0) * 8448;   // 66 wp * 128 B
    size_t xlbase  = (size_t)(n*66 + h0) * 2640;   // 66 wp * 40 B

    f32x4 acc1[4][4], acc2[4][4], acc3[4][4];
    for (int i = 0; i < 4; ++i)
        for (int t = 0; t < 4; ++t) {
            acc1[i][t] = (f32x4){0.f,0.f,0.f,0.f};
            acc2[i][t] = (f32x4){0.f,0.f,0.f,0.f};
            acc3[i][t] = (f32x4){0.f,0.f,0.f,0.f};
        }

    for (int chunk = 0; chunk < 16; ++chunk) {
        __syncthreads();                          // prev chunk compute done, all LDS free
        const char* xsrc  = XTb  + (size_t)chunk * 4460544 + xgbase;
        const char* xlsrc = XL8b + (size_t)chunk * 1393920 + xlbase;
        const char* wsrc  = WTb  + (size_t)(co_t*16 + chunk) * 73728;
        const char* wlsrc = WL8b + (size_t)(co_t*16 + chunk) * 23040;
        // X hi|mid: 50 x 1024B (last overlaps)
        for (int s = 0; s < 13; ++s) {
            int L = wv + s*4;
            if (L < 50) { int db = (L < 49) ? L*1024 : 49664; gll16(xsrc + db + lane*16, xPb + db); }
        }
        // X lo8: 16 loads (last overlaps; R7-verified pattern)
        for (int s = 0; s < 4; ++s) {
            int L = wv + s*4;
            int db = (L < 15) ? L*1024 : 14816;
            gll16(xlsrc + db + lane*16, xLb + db);
        }
        // W kh=0: hi|mid 24 loads + lo8 8 loads (R7-verified pattern)
        for (int s = 0; s < 6; ++s) {
            int L = wv + s*4;
            gll16(wsrc + L*1024 + lane*16, wPb + L*1024);
        }
        for (int s = 0; s < 2; ++s) {
            int L = wv + s*4;
            int db = (L < 7) ? L*1024 : 6656;
            gll16(wlsrc + db + lane*16, wLb + db);
        }
        __syncthreads();                          // chunk X + W[kh0] staged

#pragma unroll
        for (int kh = 0; kh < 3; ++kh) {
            if (kh) {
                __syncthreads();                  // prev kh compute done (wP/wL free)
                for (int s = 0; s < 6; ++s) {
                    int L = wv + s*4;
                    gll16(wsrc + kh*24576 + L*1024 + lane*16, wPb + L*1024);
                }
                for (int s = 0; s < 2; ++s) {
                    int L = wv + s*4;
                    int db = (L < 7) ? L*1024 : 6656;
                    gll16(wlsrc + kh*7680 + db + lane*16, wLb + db);
                }
                __syncthreads();                  // staged
            }
            int rbase = (wv + kh) * 66;
#pragma unroll
            for (int kw = 0; kw < 3; ++kw) {
                FragU a1[4], a2[4], a3[4];
#pragma unroll
                for (int i = 0; i < 4; ++i) {
                    int rW = kw*64 + i*16 + l15;
                    const char* pa = wPb + rW*128;
                    int o1 = (lg ^ (l15 & 7)) << 4;
                    a1[i].q = *(const uint4*)(pa + o1);
                    a2[i].q = *(const uint4*)(pa + (o1 ^ 64));
                    uint2 wa = *(const uint2*)(wLb + rW*40 + lg*8);
                    expand8(wa, a3[i]);
                }
#pragma unroll
                for (int t = 0; t < 4; ++t) {
                    int wp = t*16 + l15 + kw;
                    int rowB = rbase + wp;
                    const char* pb = xPb + rowB*128;
                    int o2 = (lg ^ (wp & 7)) << 4;
                    FragU b1, b2, b3;
                    b1.q = *(const uint4*)(pb + o2);
                    b2.q = *(const uint4*)(pb + (o2 ^ 64));
                    uint2 xb = *(const uint2*)(xLb + rowB*40 + lg*8);
                    expand8(xb, b3);
#pragma unroll
                    for (int i = 0; i < 4; ++i) {
                        acc1[i][t] = __builtin_amdgcn_mfma_f32_16x16x32_f16(a1[i].h, b1.h, acc1[i][t], 0, 0, 0);
                        acc2[i][t] = __builtin_amdgcn_mfma_f32_16x16x32_f16(a1[i].h, b2.h, acc2[i][t], 0, 0, 0);
                        acc2[i][t] = __builtin_amdgcn_mfma_f32_16x16x32_f16(a2[i].h, b1.h, acc2[i][t], 0, 0, 0);
                        acc3[i][t] = __builtin_amdgcn_mfma_f32_16x16x32_f16(a1[i].h, b3.h, acc3[i][t], 0, 0, 0);
                        acc3[i][t] = __builtin_amdgcn_mfma_f32_16x16x32_f16(a3[i].h, b1.h, acc3[i][t], 0, 0, 0);
                        acc3[i][t] = __builtin_amdgcn_mfma_f32_16x16x32_f16(a2[i].h, b2.h, acc3[i][t], 0, 0, 0);
                    }
                }
            }
        }
    }

    // epilogue (R3/R10-verified): co = co_t*64 + i*16 + lg*4 + r ; h = h0+wv ; wcol = t*16 + l15
    int hrow = h0 + wv;
#pragma unroll
    for (int i = 0; i < 4; ++i) {
#pragma unroll
        for (int t = 0; t < 4; ++t) {
            f32x4 v = acc1[i][t] + acc2[i][t] * (1.0f/2048.0f) + acc3[i][t] * (1.0f/4194304.0f);
#pragma unroll
            for (int r = 0; r < 4; ++r) {
                int co = co_t*64 + i*16 + lg*4 + r;
                float o = v[r] + bias[co];
                o = o > 0.f ? o : 0.f;
                base[(((size_t)(n*512 + co)) << 12) + (hrow << 6) + t*16 + l15] = o;
            }
        }
    }
}

// ===================== fallback fp32 conv (used if ws too small) =====================
__global__ __launch_bounds__(256) void conv3x3_relu(
    const float* __restrict__ x, const float* __restrict__ W,
    const float* __restrict__ bias, float* __restrict__ base)
{
    int bid  = blockIdx.x;
    int co_t = bid >> 8;
    int rem  = bid & 255;
    int n    = rem >> 5;
    int row_t= rem & 31;
    int row0 = row_t * 2;

    __shared__ float sIn[CI][4][66];
    __shared__ float sW[CI][9][64];

    int tid = threadIdx.x;
    int cg  = tid >> 4;
    int sg  = tid & 15;
    int out_r = sg >> 3;
    int wb  = (sg & 7) * 8;

    float acc[4][8];
#pragma unroll
    for (int a = 0; a < 4; ++a)
#pragma unroll
        for (int q = 0; q < 8; ++q) acc[a][q] = 0.f;

    const float* xn = x + (size_t)n * 512 * 4096;

    for (int c = 0; c < 64; ++c) {
        for (int idx = tid; idx < CI * 4 * 66; idx += 256) {
            int ci = idx / 264; int r2 = idx % 264;
            int ir = r2 / 66;   int col = r2 % 66;
            int h = row0 - 1 + ir; int w = col - 1;
            float v = 0.f;
            if ((unsigned)h < 64u && (unsigned)w < 64u)
                v = xn[(((size_t)(c * CI + ci)) << 12) + (h << 6) + w];
            sIn[ci][ir][col] = v;
        }
        {
            int co = tid >> 2; int part = tid & 3;
            const float* wp = W + ((size_t)(co_t * 64 + co) * 512 + c * CI) * 9;
#pragma unroll
            for (int q = 0; q < 18; ++q) {
                int j = part * 18 + q;
                int ci = j / 9; int k = j % 9;
                sW[ci][k][co] = wp[j];
            }
        }
        __syncthreads();

#pragma unroll
        for (int ci = 0; ci < CI; ++ci) {
            float in10[3][10];
#pragma unroll
            for (int kh = 0; kh < 3; ++kh)
#pragma unroll
                for (int q = 0; q < 10; ++q)
                    in10[kh][q] = sIn[ci][out_r + kh][wb + q];
#pragma unroll
            for (int kh = 0; kh < 3; ++kh) {
#pragma unroll
                for (int kw = 0; kw < 3; ++kw) {
                    float4 wv = *(const float4*)&sW[ci][kh * 3 + kw][cg * 4];
#pragma unroll
                    for (int wo = 0; wo < 8; ++wo) {
                        float iv = in10[kh][wo + kw];
                        acc[0][wo] += iv * wv.x;
                        acc[1][wo] += iv * wv.y;
                        acc[2][wo] += iv * wv.z;
                        acc[3][wo] += iv * wv.w;
                    }
                }
            }
        }
        __syncthreads();
    }

    int h = row0 + out_r;
#pragma unroll
    for (int a = 0; a < 4; ++a) {
        int co = co_t * 64 + cg * 4 + a;
        float b = bias[co];
        float* dst = base + (((size_t)(n * 512 + co)) << 12) + (h << 6) + wb;
#pragma unroll
        for (int wo = 0; wo < 8; ++wo) {
            float v = acc[a][wo] + b;
            dst[wo] = v > 0.f ? v : 0.f;
        }
    }
}

// ===================== 1x1 heads (256 thr: 128 pos x 2 output-halves) =====================
__global__ __launch_bounds__(256) void heads_1x1(
    const float* __restrict__ base,
    const float* __restrict__ Wc, const float* __restrict__ bc,
    const float* __restrict__ Wr, const float* __restrict__ br,
    float* __restrict__ out_score, float* __restrict__ out_reg,
    float* __restrict__ fg)
{
    __shared__ float sW[128][56];
    int tid = threadIdx.x;
    int half = tid >> 7;           // 0: outputs 0..27, 1: outputs 28..55
    int pt = tid & 127;
    int pos = blockIdx.x * 128 + pt;
    int n = pos >> 12; int hw = pos & 4095;

    float acc[28];
#pragma unroll
    for (int o = 0; o < 28; ++o) acc[o] = 0.f;

    for (int c0 = 0; c0 < 512; c0 += 128) {
        for (int idx = tid; idx < 128 * 56; idx += 256) {
            int cc = idx & 127; int o = idx >> 7;
            float wv = 0.f;
            if (o < 18)       wv = Wc[o * 512 + c0 + cc];
            else if (o < 54)  wv = Wr[(o - 18) * 512 + c0 + cc];
            sW[cc][o] = wv;
        }
        __syncthreads();
        for (int cc = 0; cc < 128; ++cc) {
            float bval = base[(((size_t)(n * 512 + c0 + cc)) << 12) + hw];
#pragma unroll
            for (int og = 0; og < 7; ++og) {
                float4 w4 = *(const float4*)&sW[cc][half*28 + og * 4];
                acc[og * 4 + 0] += bval * w4.x;
                acc[og * 4 + 1] += bval * w4.y;
                acc[og * 4 + 2] += bval * w4.z;
                acc[og * 4 + 3] += bval * w4.w;
            }
        }
        __syncthreads();
    }
#pragma unroll
    for (int o = 0; o < 28; ++o) {
        int go = half*28 + o;
        if (go < 18) acc[o] += bc[go];
        else if (go < 54) acc[o] += br[go - 18];
    }

    float* outs = out_score + (size_t)n * 73728 + (size_t)hw * 18;
    float* outr = out_reg + (size_t)n * 147456 + (size_t)hw * 36;
    if (half == 0) {
#pragma unroll
        for (int o = 0; o < 18; ++o) outs[o] = acc[o];
#pragma unroll
        for (int o = 18; o < 28; ++o) outr[o - 18] = acc[o];
#pragma unroll
        for (int a = 0; a < 9; ++a) {
            float s0 = acc[a * 2], s1 = acc[a * 2 + 1];
            float m = fmaxf(s0, s1);
            float e0 = expf(s0 - m), e1 = expf(s1 - m);
            fg[(size_t)n * 36864 + (size_t)hw * 9 + a] = e1 / (e0 + e1);
        }
    } else {
#pragma unroll
        for (int o = 0; o < 26; ++o) outr[10 + o] = acc[o];   // go 28..53 -> reg 10..35
    }
}

// ===================== decode + clip + valid + sort key =====================
__global__ __launch_bounds__(256) void decode_kernel(
    const float* __restrict__ out_reg, const float* __restrict__ fg,
    const int* __restrict__ ih_p, const int* __restrict__ iw_p,
    float4* __restrict__ boxes, unsigned long long* __restrict__ keys)
{
    int gid = blockIdx.x * 256 + threadIdx.x;
    if (gid >= 8 * 36864) return;
    int n = gid / 36864; int i = gid - n * 36864;
    int a = i % 9; int hw = i / 9; int h = hw >> 6; int w = hw & 63;
    float shx = w * 16.f, shy = h * 16.f;
    float x1 = BA[a][0] + shx, y1 = BA[a][1] + shy;
    float x2 = BA[a][2] + shx, y2 = BA[a][3] + shy;
    float wa = x2 - x1 + 1.f, ha = y2 - y1 + 1.f;
    float cxa = x1 + 0.5f * wa, cya = y1 + 0.5f * ha;
    float4 d = *(const float4*)(out_reg + (size_t)n * 147456 + (size_t)i * 4);
    float dw = fminf(fmaxf(d.z, -4.f), 4.f);
    float dh = fminf(fmaxf(d.w, -4.f), 4.f);
    float cx = d.x * wa + cxa, cy = d.y * ha + cya;
    float bw = wa * expf(dw), bh = ha * expf(dh);
    float fw = (float)(*iw_p) - 1.f, fh = (float)(*ih_p) - 1.f;
    float bx1 = fminf(fmaxf(cx - 0.5f * bw, 0.f), fw);
    float by1 = fminf(fmaxf(cy - 0.5f * bh, 0.f), fh);
    float bx2 = fminf(fmaxf(cx + 0.5f * bw, 0.f), fw);
    float by2 = fminf(fmaxf(cy + 0.5f * bh, 0.f), fh);
    boxes[gid] = make_float4(bx1, by1, bx2, by2);
    float ws_ = bx2 - bx1 + 1.f, hs_ = by2 - by1 + 1.f;
    bool valid = (ws_ >= 16.f) && (hs_ >= 16.f);
    float s = valid ? fg[gid] : -1e9f;
    unsigned int u = __float_as_uint(s);
    unsigned int ks = (u & 0x80000000u) ? ~u : (u | 0x80000000u);
    keys[gid] = ((unsigned long long)ks << 32) | (unsigned long long)(0xFFFFFFFFu - (unsigned)i);
}

// ===================== exact top-1000 via radix-select + bitonic sort =====================
__global__ __launch_bounds__(1024) void topk_kernel(
    const unsigned long long* __restrict__ keys,
    const float4* __restrict__ boxes,
    float4* __restrict__ top_boxes,
    unsigned long long* __restrict__ validmask)
{
    int b = blockIdx.x; int tid = threadIdx.x;
    const unsigned long long* kb = keys + (size_t)b * 36864;
    __shared__ unsigned int hist[256];
    __shared__ unsigned long long s_prefix;
    __shared__ int s_rank;
    __shared__ int s_cnt;
    __shared__ unsigned long long top[1024];
    if (tid == 0) { s_prefix = 0ull; s_rank = 1000; s_cnt = 0; }
    __syncthreads();

    for (int pass = 0; pass < 8; ++pass) {
        int shift = 56 - 8 * pass;
        if (tid < 256) hist[tid] = 0u;
        __syncthreads();
        unsigned long long pref = s_prefix;
        unsigned long long maskHigh = (pass == 0) ? 0ull : ((~0ull) << (shift + 8));
        for (int i = tid; i < 36864; i += 1024) {
            unsigned long long k = kb[i];
            if ((k & maskHigh) == (pref & maskHigh))
                atomicAdd(&hist[(unsigned)(k >> shift) & 255u], 1u);
        }
        __syncthreads();
        if (tid == 0) {
            int r = s_rank; int cum = 0; int B = 0;
            for (int v = 255; v >= 0; --v) {
                int c = (int)hist[v];
                if (cum + c >= r) { B = v; s_rank = r - cum; break; }
                cum += c;
            }
            s_prefix = s_prefix | ((unsigned long long)B << shift);
        }
        __syncthreads();
    }
    unsigned long long T = s_prefix;

    top[tid] = 0ull;
    __syncthreads();
    for (int i = tid; i < 36864; i += 1024) {
        unsigned long long k = kb[i];
        if (k >= T) { int p = atomicAdd(&s_cnt, 1); top[p] = k; }
    }
    __syncthreads();

    for (int k = 2; k <= 1024; k <<= 1) {
        for (int j = k >> 1; j > 0; j >>= 1) {
            int p = tid ^ j;
            unsigned long long xv = top[tid], yv = top[p];
            bool lower = tid < p;
            bool descBlock = ((tid & k) == 0);
            unsigned long long mn = xv < yv ? xv : yv;
            unsigned long long mx = xv < yv ? yv : xv;
            unsigned long long keep = descBlock ? (lower ? mx : mn) : (lower ? mn : mx);
            __syncthreads();
            top[tid] = keep;
            __syncthreads();
        }
    }

    bool validf = false;
    if (tid < 1000) {
        unsigned long long k = top[tid];
        unsigned int inv = (unsigned)(k & 0xFFFFFFFFull);
        unsigned int idx = 0xFFFFFFFFu - inv;
        unsigned int ks = (unsigned)(k >> 32);
        unsigned int u = (ks & 0x80000000u) ? (ks ^ 0x80000000u) : ~ks;
        float s = __uint_as_float(u);
        validf = (s > -5e8f);
        top_boxes[(size_t)b * 1000 + tid] = boxes[(size_t)b * 36864 + idx];
    }
    unsigned long long bal = __ballot(validf);
    if ((tid & 63) == 0) {
        int wvi = tid >> 6;
        if (wvi < 16) validmask[b * 16 + wvi] = bal;
    }
}

// ===================== NMS =====================
__global__ __launch_bounds__(256) void nms_sup(
    const float4* __restrict__ top_boxes, unsigned long long* __restrict__ sup)
{
    int b = blockIdx.y;
    __shared__ float4 sb[1000];
    int tid = threadIdx.x;
    for (int i = tid; i < 1000; i += 256) sb[i] = top_boxes[(size_t)b * 1000 + i];
    __syncthreads();
    int i = blockIdx.x * 16 + (tid >> 4);
    int wword = tid & 15;
    if (i >= 1000) return;
    float4 bi = sb[i];
    float areai = (bi.z - bi.x + 1.f) * (bi.w - bi.y + 1.f);
    unsigned long long m = 0ull;
    int j0 = wword * 64;
#pragma unroll 4
    for (int jj = 0; jj < 64; ++jj) {
        int j = j0 + jj;
        if (j > i && j < 1000) {
            float4 bj = sb[j];
            float ix1 = fmaxf(bi.x, bj.x), iy1 = fmaxf(bi.y, bj.y);
            float ix2 = fminf(bi.z, bj.z), iy2 = fminf(bi.w, bj.w);
            float iw = fmaxf(ix2 - ix1 + 1.f, 0.f), ih2 = fmaxf(iy2 - iy1 + 1.f, 0.f);
            float inter = iw * ih2;
            float areaj = (bj.z - bj.x + 1.f) * (bj.w - bj.y + 1.f);
            float iou = inter / (areai + areaj - inter);
            if (iou > 0.7f) m |= (1ull << jj);
        }
    }
    sup[((size_t)b * 1000 + i) * 16 + wword] = m;
}

// sequential NMS scan with register-group prefetch (64 rows/group, double-buffered)
__global__ __launch_bounds__(64) void nms_scan(
    const unsigned long long* __restrict__ sup,
    const unsigned long long* __restrict__ validmask,
    const float4* __restrict__ top_boxes,
    float* __restrict__ rois, float* __restrict__ counts)
{
    int b = blockIdx.x; int lane = threadIdx.x;
    const unsigned long long* supb = sup + (size_t)b * 16000;
    int sub = lane >> 4;
    int word = lane & 15;

    unsigned long long bufA[16], bufB[16];
    unsigned long long remv = 0ull, keepw = 0ull;

#define PRELOAD(dst, g1)                                                   \
    _Pragma("unroll")                                                      \
    for (int k = 0; k < 16; ++k) {                                         \
        int r = (g1)*64 + k*4 + sub;                                       \
        if (r > 999) r = 999;                                              \
        dst[k] = supb[(size_t)r*16 + word];                                \
    }

#define PROCESS(buf, g)                                                    \
    _Pragma("unroll")                                                      \
    for (int ii = 0; ii < 64; ++ii) {                                      \
        int i = (g)*64 + ii;                                               \
        if (i < 1000) {                                                    \
            unsigned long long rw = __shfl(remv, (g), 64);                 \
            bool kept = !((rw >> ii) & 1ull);                              \
            unsigned long long rowv = __shfl(buf[ii>>2], ((ii&3)<<4) | word, 64); \
            if (kept) {                                                    \
                remv |= rowv;                                              \
                if (lane == (g)) keepw |= (1ull << ii);                    \
            }                                                              \
        }                                                                  \
    }

    PRELOAD(bufA, 0)
    for (int gp = 0; gp < 8; ++gp) {
        PRELOAD(bufB, gp*2 + 1)
        PROCESS(bufA, gp*2)
        if (gp < 7) { PRELOAD(bufA, gp*2 + 2) }
        PROCESS(bufB, gp*2 + 1)
    }
#undef PRELOAD
#undef PROCESS

    if (lane < 16) keepw &= validmask[b * 16 + lane];
    int cnt = (lane < 16) ? __popcll(keepw) : 0;
    int inc = cnt;
    for (int off = 1; off < 16; off <<= 1) {
        int t = __shfl_up(inc, off, 64);
        if (lane >= off) inc += t;
    }
    int total = __shfl(inc, 15, 64);
    int pre = inc - cnt;
    int count = total < 300 ? total : 300;

    float4* ro = (float4*)(rois + (size_t)b * 1200);
    for (int s = count + lane; s < 300; s += 64)
        ro[s] = make_float4(0.f, 0.f, 0.f, 0.f);
    for (int i = lane; i < 1000; i += 64) {
        int w = i >> 6, bit = i & 63;
        unsigned long long kw = __shfl(keepw, w, 64);
        int prew = __shfl(pre, w, 64);
        if ((kw >> bit) & 1ull) {
            int rank = prew + __popcll(kw & ((1ull << bit) - 1ull));
            if (rank < 300)
                ro[rank] = top_boxes[(size_t)b * 1000 + i];
        }
    }
    if (lane == 0) counts[b] = (float)count;
}

// ===================== launch =====================
extern "C" void kernel_launch(void* const* d_in, const int* in_sizes, int n_in,
                              void* d_out, int out_size, void* d_ws, size_t ws_size,
                              hipStream_t stream) {
    const float* x  = (const float*)d_in[0];
    const float* Wb = (const float*)d_in[1];
    const float* bb = (const float*)d_in[2];
    const float* Wc = (const float*)d_in[3];
    const float* bc = (const float*)d_in[4];
    const float* Wr = (const float*)d_in[5];
    const float* br = (const float*)d_in[6];
    const int* ih   = (const int*)d_in[7];
    const int* iw   = (const int*)d_in[8];

    float* out       = (float*)d_out;
    float* out_score = out;
    float* out_reg   = out + 589824;
    float* rois      = out + 589824 + 1179648;
    float* counts    = rois + 9600;

    char* ws = (char*)d_ws;
    float* fg                      = (float*)(ws);                        // 1,179,648
    float4* boxes                  = (float4*)(ws + 1179648);             // 4,718,592
    unsigned long long* keys       = (unsigned long long*)(ws + 5898240); // 2,359,296
    float4* top_boxes              = (float4*)(ws + 8257536);             // 128,000
    unsigned long long* sup        = (unsigned long long*)(ws + 8385536); // 1,024,000
    unsigned long long* validmask  = (unsigned long long*)(ws + 9409536); // 1,024
    float* base                    = (float*)(ws + 9410560);              // 67,108,864
    unsigned short* XT             = (unsigned short*)(ws + 76519424);    // 71,368,704
    unsigned short* WT2            = (unsigned short*)(ws + 147888128);   //  9,437,184
    unsigned char* XL8             = (unsigned char*)(ws + 157325312);    // 22,302,720
    unsigned char* WL8             = (unsigned char*)(ws + 179628032);    //  2,949,120
    const size_t NEED_MFMA = 182577152;

    if (ws_size >= NEED_MFMA) {
        split_x_kernel<<<16*8*66, 256, 0, stream>>>(x, XT, XL8);
        split_w_kernel<<<(4718592 + 2949120 + 255)/256, 256, 0, stream>>>(Wb, WT2, WL8);
        conv3x3_mfma<<<1024, 256, 0, stream>>>(XT, WT2, XL8, WL8, bb, base);
    } else {
        conv3x3_relu<<<2048, 256, 0, stream>>>(x, Wb, bb, base);
    }
    heads_1x1<<<256, 256, 0, stream>>>(base, Wc, bc, Wr, br, out_score, out_reg, fg);
    decode_kernel<<<1152, 256, 0, stream>>>(out_reg, fg, ih, iw, boxes, keys);
    topk_kernel<<<8, 1024, 0, stream>>>(keys, boxes, top_boxes, validmask);
    nms_sup<<<dim3(63, 8), 256, 0, stream>>>(top_boxes, sup);
    nms_scan<<<8, 64, 0, stream>>>(sup, validmask, top_boxes, rois, counts);
}